// Round 3
// baseline (468.003 us; speedup 1.0000x reference)
//
#include <hip/hip_runtime.h>
#include <hip/hip_cooperative_groups.h>

namespace cg = cooperative_groups;

namespace {
constexpr int GX = 200, GY = 200, GZ = 20;
constexpr int NVOX = GX * GY * GZ;            // 800000
constexpr float VMINX = -40.f, VMINY = -40.f, VMINZ = -4.f;
constexpr float VMAXX =  40.f, VMAXY =  40.f, VMAXZ =  4.f;
constexpr float VS    = 0.4f;                 // voxel size
constexpr float HVS   = 0.2f;                 // 0.5 * voxel size
constexpr float SIGF  = 3.0f;                 // sigma factor

constexpr int TILE   = 4;                     // tile is 4x4 in x,y; full z column
constexpr int TX     = GX / TILE;             // 50
constexpr int TY     = GY / TILE;             // 50
constexpr int NTILES = TX * TY;               // 2500
constexpr int CAP    = 128;                   // max gaussians per tile list (avg ~34)
constexpr int BLK    = 64;                    // one wave per block/tile
}

// Per-Gaussian setup: covariance from quat+scales, analytic inverse, voxel
// window (trunc-toward-zero casts + clamps + 8-offset cap, matching ref).
__device__ __forceinline__ bool gauss_setup(
    const float* __restrict__ means, const float* __restrict__ opacs,
    const float* __restrict__ scales, const float* __restrict__ rots,
    int g,
    int& gx0, int& gx1, int& gy0, int& gy1, int& gz0, int& gz1,
    float& i00, float& i01, float& i02, float& i11, float& i12, float& i22,
    float& mx, float& my, float& mz, float& op)
{
    op = opacs[g];
    mx = means[3*g+0]; my = means[3*g+1]; mz = means[3*g+2];
    const float sx = scales[3*g+0], sy = scales[3*g+1], sz = scales[3*g+2];
    const float q0 = rots[4*g+0], q1 = rots[4*g+1], q2 = rots[4*g+2], q3 = rots[4*g+3];

    const float qn = sqrtf(q0*q0 + q1*q1 + q2*q2 + q3*q3 + 1e-8f);
    const float r = q0/qn, x = q1/qn, y = q2/qn, z = q3/qn;

    const float R00 = 1.f - 2.f*(y*y + z*z), R01 = 2.f*(x*y - r*z), R02 = 2.f*(x*z + r*y);
    const float R10 = 2.f*(x*y + r*z), R11 = 1.f - 2.f*(x*x + z*z), R12 = 2.f*(y*z - r*x);
    const float R20 = 2.f*(x*z - r*y), R21 = 2.f*(y*z + r*x), R22 = 1.f - 2.f*(x*x + y*y);

    const float s0 = sx*sx, s1 = sy*sy, s2 = sz*sz;
    const float c00 = R00*R00*s0 + R01*R01*s1 + R02*R02*s2;
    const float c01 = R00*R10*s0 + R01*R11*s1 + R02*R12*s2;
    const float c02 = R00*R20*s0 + R01*R21*s1 + R02*R22*s2;
    const float c11 = R10*R10*s0 + R11*R11*s1 + R12*R12*s2;
    const float c12 = R10*R20*s0 + R11*R21*s1 + R12*R22*s2;
    const float c22 = R20*R20*s0 + R21*R21*s1 + R22*R22*s2;

    const float sgx = SIGF * sqrtf(c00), sgy = SIGF * sqrtf(c11), sgz = SIGF * sqrtf(c22);
    const float bminx = mx - sgx, bminy = my - sgy, bminz = mz - sgz;
    const float bmaxx = mx + sgx, bmaxy = my + sgy, bmaxz = mz + sgz;

    const bool keep = (bmaxx > VMINX) && (bmaxy > VMINY) && (bmaxz > VMINZ)
                   && (bminx < VMAXX) && (bminy < VMAXY) && (bminz < VMAXZ)
                   && (op > 1e-4f);
    if (!keep) return false;

    gx0 = max((int)((bminx - VMINX) / VS), 0);
    gy0 = max((int)((bminy - VMINY) / VS), 0);
    gz0 = max((int)((bminz - VMINZ) / VS), 0);
    gx1 = min((int)((bmaxx - VMINX) / VS), GX - 1);
    gy1 = min((int)((bmaxy - VMINY) / VS), GY - 1);
    gz1 = min((int)((bmaxz - VMINZ) / VS), GZ - 1);
    // reference enumerates only offsets 0..7 from idx_min
    gx1 = min(gx1, gx0 + 7);
    gy1 = min(gy1, gy0 + 7);
    gz1 = min(gz1, gz0 + 7);
    if (gx1 < gx0 || gy1 < gy0 || gz1 < gz0) return false;

    // analytic inverse of symmetric 3x3
    const float m00 = c11*c22 - c12*c12;
    const float m01 = c02*c12 - c01*c22;
    const float m02 = c01*c12 - c02*c11;
    const float det = c00*m00 + c01*m01 + c02*m02;
    const float id  = 1.f / det;
    i00 = m00*id; i01 = m01*id; i02 = m02*id;
    i11 = (c00*c22 - c02*c02)*id;
    i12 = (c01*c02 - c00*c12)*id;
    i22 = (c00*c11 - c01*c01)*id;
    return true;
}

// Single cooperative kernel: zero counters -> bin -> gather, with grid syncs.
// 2500 blocks x 64 threads (one wave per 4x4x20 tile).
__global__ __launch_bounds__(BLK) void voxel_fused(
    const float* __restrict__ means, const float* __restrict__ opacs,
    const float* __restrict__ scales, const float* __restrict__ rots,
    const float* __restrict__ feats,
    int* __restrict__ counts, int* __restrict__ entries,
    float* __restrict__ density, float* __restrict__ gfeat, int N)
{
    cg::grid_group grid = cg::this_grid();
    const int tid = threadIdx.x;
    const int gid = blockIdx.x * BLK + tid;

    // ---- phase 0: zero tile counters (ws is 0xAA-poisoned each call) ----
    if (gid < NTILES) counts[gid] = 0;
    grid.sync();

    // ---- phase 1: bin gaussians into 4x4 xy tiles (<=3x3 tiles each) ----
    if (gid < N) {
        int gx0, gx1, gy0, gy1, gz0, gz1;
        float i00,i01,i02,i11,i12,i22, mx,my,mz, op;
        if (gauss_setup(means, opacs, scales, rots, gid,
                        gx0,gx1,gy0,gy1,gz0,gz1, i00,i01,i02,i11,i12,i22, mx,my,mz, op)) {
            const int tx0 = gx0 >> 2, tx1 = gx1 >> 2;
            const int ty0 = gy0 >> 2, ty1 = gy1 >> 2;
            for (int tx = tx0; tx <= tx1; ++tx)
                for (int ty = ty0; ty <= ty1; ++ty) {
                    const int t = tx * TY + ty;
                    const int slot = atomicAdd(&counts[t], 1);
                    if (slot < CAP) entries[t * CAP + slot] = gid;
                }
        }
    }
    grid.sync();

    // ---- phase 2: gather, one tile per block ----
    __shared__ float gs[CAP][20];   // [i00..i22, mx,my,mz, op, f0..f7, win0, win1]

    const int tile = blockIdx.x;
    const int ttx = tile / TY, tty = tile % TY;
    const int cnt = min(counts[tile], CAP);

    for (int j = tid; j < cnt; j += BLK) {
        const int g = entries[tile * CAP + j];
        int gx0, gx1, gy0, gy1, gz0, gz1;
        float i00,i01,i02,i11,i12,i22, mx,my,mz, op;
        gauss_setup(means, opacs, scales, rots, g,
                    gx0,gx1,gy0,gy1,gz0,gz1, i00,i01,i02,i11,i12,i22, mx,my,mz, op);
        float* G = gs[j];
        G[0]=i00; G[1]=i01; G[2]=i02; G[3]=i11; G[4]=i12; G[5]=i22;
        G[6]=mx; G[7]=my; G[8]=mz; G[9]=op;
        const float4 f0 = *(const float4*)(feats + 8*g);
        const float4 f1 = *(const float4*)(feats + 8*g + 4);
        G[10]=f0.x; G[11]=f0.y; G[12]=f0.z; G[13]=f0.w;
        G[14]=f1.x; G[15]=f1.y; G[16]=f1.z; G[17]=f1.w;
        G[18] = __int_as_float(gx0 | (gy0<<8) | (gz0<<16));
        G[19] = __int_as_float(gx1 | (gy1<<8) | (gz1<<16));
    }
    __syncthreads();

    const int lx = tid & 3, ly = (tid >> 2) & 3, zs = (tid >> 4) * 5;
    const int vx = ttx * TILE + lx, vy = tty * TILE + ly;
    const float cx = (float)vx * VS + VMINX + HVS;
    const float cy = (float)vy * VS + VMINY + HVS;

    float den[5] = {0.f, 0.f, 0.f, 0.f, 0.f};
    float ft[5][8] = {};

    #pragma unroll 2
    for (int j = 0; j < cnt; ++j) {
        const float* G = gs[j];
        const int w0 = __float_as_int(G[18]);
        const int w1 = __float_as_int(G[19]);
        const int gx0 = w0 & 255, gy0 = (w0 >> 8) & 255, gz0 = (w0 >> 16) & 255;
        const int gx1 = w1 & 255, gy1 = (w1 >> 8) & 255, gz1 = (w1 >> 16) & 255;
        if (vx < gx0 || vx > gx1 || vy < gy0 || vy > gy1) continue;

        const float ddx = cx - G[6], ddy = cy - G[7];
        const float i00 = G[0], i01 = G[1], i02 = G[2];
        const float i11 = G[3], i12 = G[4], i22 = G[5];
        const float base = i00*ddx*ddx + 2.f*i01*ddx*ddy + i11*ddy*ddy;
        const float bz   = 2.f*(i02*ddx + i12*ddy);
        const float mz = G[8], op = G[9];
        const float f[8] = {G[10],G[11],G[12],G[13],G[14],G[15],G[16],G[17]};

        #pragma unroll
        for (int k = 0; k < 5; ++k) {
            const int vz = zs + k;
            if (vz < gz0 || vz > gz1) continue;
            const float ddz = ((float)vz * VS + VMINZ + HVS) - mz;
            const float w = op * __expf(-0.5f * (base + ddz * (bz + i22 * ddz)));
            den[k] += w;
            #pragma unroll
            for (int c = 0; c < 8; ++c) ft[k][c] += w * f[c];
        }
    }

    #pragma unroll
    for (int k = 0; k < 5; ++k) {
        const int vz = zs + k;
        const int flat = (vx * GY + vy) * GZ + vz;
        density[flat] = den[k];
        const float inv = 1.f / fmaxf(den[k], 1e-6f);
        float4 a = make_float4(ft[k][0]*inv, ft[k][1]*inv, ft[k][2]*inv, ft[k][3]*inv);
        float4 b = make_float4(ft[k][4]*inv, ft[k][5]*inv, ft[k][6]*inv, ft[k][7]*inv);
        *(float4*)(gfeat + (size_t)flat * 8)     = a;
        *(float4*)(gfeat + (size_t)flat * 8 + 4) = b;
    }
}

extern "C" void kernel_launch(void* const* d_in, const int* in_sizes, int n_in,
                              void* d_out, int out_size, void* d_ws, size_t ws_size,
                              hipStream_t stream)
{
    const float* means  = (const float*)d_in[0];
    const float* opacs  = (const float*)d_in[1];
    const float* scales = (const float*)d_in[2];
    const float* rots   = (const float*)d_in[3];
    const float* feats  = (const float*)d_in[4];

    float* density = (float*)d_out;           // [V]
    float* gfeat   = density + NVOX;          // [V, 8]
    int N = in_sizes[0] / 3;                  // means3d is [B, N, 3], B=1

    int* counts  = (int*)d_ws;                // [2500]
    int* entries = counts + NTILES;           // [2500 * 128]

    void* args[] = {
        (void*)&means, (void*)&opacs, (void*)&scales, (void*)&rots, (void*)&feats,
        (void*)&counts, (void*)&entries, (void*)&density, (void*)&gfeat, (void*)&N
    };
    hipLaunchCooperativeKernel((const void*)voxel_fused,
                               dim3(NTILES), dim3(BLK), args, 0, stream);
}

// Round 4
// 109.737 us; speedup vs baseline: 4.2648x; 4.2648x over previous
//
#include <hip/hip_runtime.h>

namespace {
constexpr int GX = 200, GY = 200, GZ = 20;
constexpr int NVOX = GX * GY * GZ;            // 800000
constexpr float VMINX = -40.f, VMINY = -40.f, VMINZ = -4.f;
constexpr float VMAXX =  40.f, VMAXY =  40.f, VMAXZ =  4.f;
constexpr float VS    = 0.4f;                 // voxel size
constexpr float HVS   = 0.2f;                 // 0.5 * voxel size
constexpr float SIGF  = 3.0f;                 // sigma factor

constexpr int TILE   = 4;                     // tile is 4x4 in x,y; full z column
constexpr int TX     = GX / TILE;             // 50
constexpr int TY     = GY / TILE;             // 50
constexpr int NTILES = TX * TY;               // 2500
constexpr int CAP    = 128;                   // max gaussians per tile list (avg ~40)
constexpr int PSTRIDE = 20;                   // floats per param record
}

// Per-Gaussian setup: covariance from quat+scales, analytic inverse, voxel
// window (trunc-toward-zero casts + clamps + 8-offset cap, matching ref).
__device__ __forceinline__ bool gauss_setup(
    const float* __restrict__ means, const float* __restrict__ opacs,
    const float* __restrict__ scales, const float* __restrict__ rots,
    int g,
    int& gx0, int& gx1, int& gy0, int& gy1, int& gz0, int& gz1,
    float& i00, float& i01, float& i02, float& i11, float& i12, float& i22,
    float& mx, float& my, float& mz, float& op)
{
    op = opacs[g];
    mx = means[3*g+0]; my = means[3*g+1]; mz = means[3*g+2];
    const float sx = scales[3*g+0], sy = scales[3*g+1], sz = scales[3*g+2];
    const float q0 = rots[4*g+0], q1 = rots[4*g+1], q2 = rots[4*g+2], q3 = rots[4*g+3];

    const float qn = sqrtf(q0*q0 + q1*q1 + q2*q2 + q3*q3 + 1e-8f);
    const float r = q0/qn, x = q1/qn, y = q2/qn, z = q3/qn;

    const float R00 = 1.f - 2.f*(y*y + z*z), R01 = 2.f*(x*y - r*z), R02 = 2.f*(x*z + r*y);
    const float R10 = 2.f*(x*y + r*z), R11 = 1.f - 2.f*(x*x + z*z), R12 = 2.f*(y*z - r*x);
    const float R20 = 2.f*(x*z - r*y), R21 = 2.f*(y*z + r*x), R22 = 1.f - 2.f*(x*x + y*y);

    const float s0 = sx*sx, s1 = sy*sy, s2 = sz*sz;
    const float c00 = R00*R00*s0 + R01*R01*s1 + R02*R02*s2;
    const float c01 = R00*R10*s0 + R01*R11*s1 + R02*R12*s2;
    const float c02 = R00*R20*s0 + R01*R21*s1 + R02*R22*s2;
    const float c11 = R10*R10*s0 + R11*R11*s1 + R12*R12*s2;
    const float c12 = R10*R20*s0 + R11*R21*s1 + R12*R22*s2;
    const float c22 = R20*R20*s0 + R21*R21*s1 + R22*R22*s2;

    const float sgx = SIGF * sqrtf(c00), sgy = SIGF * sqrtf(c11), sgz = SIGF * sqrtf(c22);
    const float bminx = mx - sgx, bminy = my - sgy, bminz = mz - sgz;
    const float bmaxx = mx + sgx, bmaxy = my + sgy, bmaxz = mz + sgz;

    const bool keep = (bmaxx > VMINX) && (bmaxy > VMINY) && (bmaxz > VMINZ)
                   && (bminx < VMAXX) && (bminy < VMAXY) && (bminz < VMAXZ)
                   && (op > 1e-4f);
    if (!keep) return false;

    gx0 = max((int)((bminx - VMINX) / VS), 0);
    gy0 = max((int)((bminy - VMINY) / VS), 0);
    gz0 = max((int)((bminz - VMINZ) / VS), 0);
    gx1 = min((int)((bmaxx - VMINX) / VS), GX - 1);
    gy1 = min((int)((bmaxy - VMINY) / VS), GY - 1);
    gz1 = min((int)((bmaxz - VMINZ) / VS), GZ - 1);
    // reference enumerates only offsets 0..7 from idx_min
    gx1 = min(gx1, gx0 + 7);
    gy1 = min(gy1, gy0 + 7);
    gz1 = min(gz1, gz0 + 7);
    if (gx1 < gx0 || gy1 < gy0 || gz1 < gz0) return false;

    // analytic inverse of symmetric 3x3
    const float m00 = c11*c22 - c12*c12;
    const float m01 = c02*c12 - c01*c22;
    const float m02 = c01*c12 - c02*c11;
    const float det = c00*m00 + c01*m01 + c02*m02;
    const float id  = 1.f / det;
    i00 = m00*id; i01 = m01*id; i02 = m02*id;
    i11 = (c00*c22 - c02*c02)*id;
    i12 = (c01*c02 - c00*c12)*id;
    i22 = (c00*c11 - c01*c01)*id;
    return true;
}

// One thread per Gaussian: compute setup once, write a 20-float param record,
// append id to each touched 4x4 tile's list (<=3x3 tiles).
__global__ __launch_bounds__(64) void voxel_bin(
    const float* __restrict__ means, const float* __restrict__ opacs,
    const float* __restrict__ scales, const float* __restrict__ rots,
    const float* __restrict__ feats,
    int* __restrict__ counts, int* __restrict__ entries,
    float* __restrict__ params, int N)
{
    const int g = blockIdx.x * blockDim.x + threadIdx.x;
    if (g >= N) return;
    int gx0, gx1, gy0, gy1, gz0, gz1;
    float i00,i01,i02,i11,i12,i22, mx,my,mz, op;
    if (!gauss_setup(means, opacs, scales, rots, g,
                     gx0,gx1,gy0,gy1,gz0,gz1, i00,i01,i02,i11,i12,i22, mx,my,mz, op))
        return;

    float* P = params + (size_t)g * PSTRIDE;
    const float4 f0 = *(const float4*)(feats + 8*g);
    const float4 f1 = *(const float4*)(feats + 8*g + 4);
    *(float4*)(P + 0)  = make_float4(i00, i01, i02, i11);
    *(float4*)(P + 4)  = make_float4(i12, i22, mx, my);
    *(float4*)(P + 8)  = make_float4(mz, op,
                                     __int_as_float(gx0 | (gy0<<8) | (gz0<<16)),
                                     __int_as_float(gx1 | (gy1<<8) | (gz1<<16)));
    *(float4*)(P + 12) = f0;
    *(float4*)(P + 16) = f1;

    const int tx0 = gx0 >> 2, tx1 = gx1 >> 2;
    const int ty0 = gy0 >> 2, ty1 = gy1 >> 2;
    for (int tx = tx0; tx <= tx1; ++tx)
        for (int ty = ty0; ty <= ty1; ++ty) {
            const int t = tx * TY + ty;
            const int slot = atomicAdd(&counts[t], 1);
            if (slot < CAP) entries[t * CAP + slot] = g;
        }
}

// One wave per 4x4x20 tile. Stage param records in LDS, each thread
// accumulates a 5-voxel z-column segment in registers, writes once (norm fused).
__global__ __launch_bounds__(64) void voxel_gather(
    const float* __restrict__ params,
    const int* __restrict__ counts, const int* __restrict__ entries,
    float* __restrict__ density, float* __restrict__ gfeat)
{
    __shared__ float gs[CAP][PSTRIDE];

    const int tile = blockIdx.x;
    const int ttx = tile / TY, tty = tile % TY;
    const int tid = threadIdx.x;
    const int cnt = min(counts[tile], CAP);

    for (int j = tid; j < cnt; j += 64) {
        const int g = entries[tile * CAP + j];
        const float* P = params + (size_t)g * PSTRIDE;
        float* G = gs[j];
        #pragma unroll
        for (int q = 0; q < 5; ++q)
            *(float4*)(G + 4*q) = *(const float4*)(P + 4*q);
    }
    __syncthreads();

    const int lx = tid & 3, ly = (tid >> 2) & 3, zs = (tid >> 4) * 5;
    const int vx = ttx * TILE + lx, vy = tty * TILE + ly;
    const float cx = (float)vx * VS + VMINX + HVS;
    const float cy = (float)vy * VS + VMINY + HVS;

    float den[5] = {0.f, 0.f, 0.f, 0.f, 0.f};
    float ft[5][8] = {};

    #pragma unroll 2
    for (int j = 0; j < cnt; ++j) {
        const float* G = gs[j];
        const int w0 = __float_as_int(G[10]);
        const int w1 = __float_as_int(G[11]);
        const int gx0 = w0 & 255, gy0 = (w0 >> 8) & 255, gz0 = (w0 >> 16) & 255;
        const int gx1 = w1 & 255, gy1 = (w1 >> 8) & 255, gz1 = (w1 >> 16) & 255;
        if (vx < gx0 || vx > gx1 || vy < gy0 || vy > gy1) continue;

        const float ddx = cx - G[6], ddy = cy - G[7];
        const float i00 = G[0], i01 = G[1], i02 = G[2];
        const float i11 = G[3], i12 = G[4], i22 = G[5];
        const float base = i00*ddx*ddx + 2.f*i01*ddx*ddy + i11*ddy*ddy;
        const float bz   = 2.f*(i02*ddx + i12*ddy);
        const float mz = G[8], op = G[9];
        const float f[8] = {G[12],G[13],G[14],G[15],G[16],G[17],G[18],G[19]};

        #pragma unroll
        for (int k = 0; k < 5; ++k) {
            const int vz = zs + k;
            if (vz < gz0 || vz > gz1) continue;
            const float ddz = ((float)vz * VS + VMINZ + HVS) - mz;
            const float w = op * __expf(-0.5f * (base + ddz * (bz + i22 * ddz)));
            den[k] += w;
            #pragma unroll
            for (int c = 0; c < 8; ++c) ft[k][c] += w * f[c];
        }
    }

    #pragma unroll
    for (int k = 0; k < 5; ++k) {
        const int vz = zs + k;
        const int flat = (vx * GY + vy) * GZ + vz;
        density[flat] = den[k];
        const float inv = 1.f / fmaxf(den[k], 1e-6f);
        float4 a = make_float4(ft[k][0]*inv, ft[k][1]*inv, ft[k][2]*inv, ft[k][3]*inv);
        float4 b = make_float4(ft[k][4]*inv, ft[k][5]*inv, ft[k][6]*inv, ft[k][7]*inv);
        *(float4*)(gfeat + (size_t)flat * 8)     = a;
        *(float4*)(gfeat + (size_t)flat * 8 + 4) = b;
    }
}

extern "C" void kernel_launch(void* const* d_in, const int* in_sizes, int n_in,
                              void* d_out, int out_size, void* d_ws, size_t ws_size,
                              hipStream_t stream)
{
    const float* means  = (const float*)d_in[0];
    const float* opacs  = (const float*)d_in[1];
    const float* scales = (const float*)d_in[2];
    const float* rots   = (const float*)d_in[3];
    const float* feats  = (const float*)d_in[4];

    float* density = (float*)d_out;           // [V]
    float* gfeat   = density + NVOX;          // [V, 8]
    const int N = in_sizes[0] / 3;            // means3d is [B, N, 3], B=1

    int*   counts  = (int*)d_ws;              // [2500]
    int*   entries = counts + NTILES;         // [2500 * 128]
    float* params  = (float*)(entries + NTILES * CAP);  // [N * 20]

    // ws is poisoned 0xAA before every timed call; zero the tile counters
    hipMemsetAsync(counts, 0, NTILES * sizeof(int), stream);

    voxel_bin<<<(N + 63) / 64, 64, 0, stream>>>(means, opacs, scales, rots, feats,
                                                counts, entries, params, N);
    voxel_gather<<<NTILES, 64, 0, stream>>>(params, counts, entries, density, gfeat);
}

// Round 5
// 105.105 us; speedup vs baseline: 4.4527x; 1.0441x over previous
//
#include <hip/hip_runtime.h>

namespace {
constexpr int GX = 200, GY = 200, GZ = 20;
constexpr int NVOX = GX * GY * GZ;            // 800000
constexpr float VMINX = -40.f, VMINY = -40.f, VMINZ = -4.f;
constexpr float VMAXX =  40.f, VMAXY =  40.f, VMAXZ =  4.f;
constexpr float VS    = 0.4f;                 // voxel size
constexpr float HVS   = 0.2f;                 // 0.5 * voxel size
constexpr float SIGF  = 3.0f;                 // sigma factor

constexpr int TILE   = 4;                     // 4x4 in x,y
constexpr int ZSEG   = 4;                     // 4 voxels in z
constexpr int TX     = GX / TILE;             // 50
constexpr int TY     = GY / TILE;             // 50
constexpr int TZ     = GZ / ZSEG;             // 5
constexpr int NTILES = TX * TY * TZ;          // 12500
constexpr int CAP    = 128;                   // max gaussians per list (avg ~15)
constexpr int PSTRIDE = 20;                   // floats per param record
}

// Per-Gaussian setup: covariance from quat+scales, analytic inverse, voxel
// window (trunc-toward-zero casts + clamps + 8-offset cap, matching ref).
__device__ __forceinline__ bool gauss_setup(
    const float* __restrict__ means, const float* __restrict__ opacs,
    const float* __restrict__ scales, const float* __restrict__ rots,
    int g,
    int& gx0, int& gx1, int& gy0, int& gy1, int& gz0, int& gz1,
    float& i00, float& i01, float& i02, float& i11, float& i12, float& i22,
    float& mx, float& my, float& mz, float& op)
{
    op = opacs[g];
    mx = means[3*g+0]; my = means[3*g+1]; mz = means[3*g+2];
    const float sx = scales[3*g+0], sy = scales[3*g+1], sz = scales[3*g+2];
    const float q0 = rots[4*g+0], q1 = rots[4*g+1], q2 = rots[4*g+2], q3 = rots[4*g+3];

    const float qn = sqrtf(q0*q0 + q1*q1 + q2*q2 + q3*q3 + 1e-8f);
    const float r = q0/qn, x = q1/qn, y = q2/qn, z = q3/qn;

    const float R00 = 1.f - 2.f*(y*y + z*z), R01 = 2.f*(x*y - r*z), R02 = 2.f*(x*z + r*y);
    const float R10 = 2.f*(x*y + r*z), R11 = 1.f - 2.f*(x*x + z*z), R12 = 2.f*(y*z - r*x);
    const float R20 = 2.f*(x*z - r*y), R21 = 2.f*(y*z + r*x), R22 = 1.f - 2.f*(x*x + y*y);

    const float s0 = sx*sx, s1 = sy*sy, s2 = sz*sz;
    const float c00 = R00*R00*s0 + R01*R01*s1 + R02*R02*s2;
    const float c01 = R00*R10*s0 + R01*R11*s1 + R02*R12*s2;
    const float c02 = R00*R20*s0 + R01*R21*s1 + R02*R22*s2;
    const float c11 = R10*R10*s0 + R11*R11*s1 + R12*R12*s2;
    const float c12 = R10*R20*s0 + R11*R21*s1 + R12*R22*s2;
    const float c22 = R20*R20*s0 + R21*R21*s1 + R22*R22*s2;

    const float sgx = SIGF * sqrtf(c00), sgy = SIGF * sqrtf(c11), sgz = SIGF * sqrtf(c22);
    const float bminx = mx - sgx, bminy = my - sgy, bminz = mz - sgz;
    const float bmaxx = mx + sgx, bmaxy = my + sgy, bmaxz = mz + sgz;

    const bool keep = (bmaxx > VMINX) && (bmaxy > VMINY) && (bmaxz > VMINZ)
                   && (bminx < VMAXX) && (bminy < VMAXY) && (bminz < VMAXZ)
                   && (op > 1e-4f);
    if (!keep) return false;

    gx0 = max((int)((bminx - VMINX) / VS), 0);
    gy0 = max((int)((bminy - VMINY) / VS), 0);
    gz0 = max((int)((bminz - VMINZ) / VS), 0);
    gx1 = min((int)((bmaxx - VMINX) / VS), GX - 1);
    gy1 = min((int)((bmaxy - VMINY) / VS), GY - 1);
    gz1 = min((int)((bmaxz - VMINZ) / VS), GZ - 1);
    // reference enumerates only offsets 0..7 from idx_min
    gx1 = min(gx1, gx0 + 7);
    gy1 = min(gy1, gy0 + 7);
    gz1 = min(gz1, gz0 + 7);
    if (gx1 < gx0 || gy1 < gy0 || gz1 < gz0) return false;

    // analytic inverse of symmetric 3x3
    const float m00 = c11*c22 - c12*c12;
    const float m01 = c02*c12 - c01*c22;
    const float m02 = c01*c12 - c02*c11;
    const float det = c00*m00 + c01*m01 + c02*m02;
    const float id  = 1.f / det;
    i00 = m00*id; i01 = m01*id; i02 = m02*id;
    i11 = (c00*c22 - c02*c02)*id;
    i12 = (c01*c02 - c00*c12)*id;
    i22 = (c00*c11 - c01*c01)*id;
    return true;
}

// One thread per Gaussian: compute setup once, write a 20-float param record,
// append id to each touched (4x4 xy tile, 4-z segment) list (<=3x3x3 lists).
__global__ __launch_bounds__(64) void voxel_bin(
    const float* __restrict__ means, const float* __restrict__ opacs,
    const float* __restrict__ scales, const float* __restrict__ rots,
    const float* __restrict__ feats,
    int* __restrict__ counts, int* __restrict__ entries,
    float* __restrict__ params, int N)
{
    const int g = blockIdx.x * blockDim.x + threadIdx.x;
    if (g >= N) return;
    int gx0, gx1, gy0, gy1, gz0, gz1;
    float i00,i01,i02,i11,i12,i22, mx,my,mz, op;
    if (!gauss_setup(means, opacs, scales, rots, g,
                     gx0,gx1,gy0,gy1,gz0,gz1, i00,i01,i02,i11,i12,i22, mx,my,mz, op))
        return;

    float* P = params + (size_t)g * PSTRIDE;
    const float4 f0 = *(const float4*)(feats + 8*g);
    const float4 f1 = *(const float4*)(feats + 8*g + 4);
    *(float4*)(P + 0)  = make_float4(i00, i01, i02, i11);
    *(float4*)(P + 4)  = make_float4(i12, i22, mx, my);
    *(float4*)(P + 8)  = make_float4(mz, op,
                                     __int_as_float(gx0 | (gy0<<8) | (gz0<<16)),
                                     __int_as_float(gx1 | (gy1<<8) | (gz1<<16)));
    *(float4*)(P + 12) = f0;
    *(float4*)(P + 16) = f1;

    const int tx0 = gx0 >> 2, tx1 = gx1 >> 2;
    const int ty0 = gy0 >> 2, ty1 = gy1 >> 2;
    const int tz0 = gz0 >> 2, tz1 = gz1 >> 2;
    for (int tx = tx0; tx <= tx1; ++tx)
        for (int ty = ty0; ty <= ty1; ++ty)
            for (int tz = tz0; tz <= tz1; ++tz) {
                const int t = (tx * TY + ty) * TZ + tz;
                const int slot = atomicAdd(&counts[t], 1);
                if (slot < CAP) entries[t * CAP + slot] = g;
            }
}

// One wave per 4x4x4 voxel block: one voxel per lane. Stage param records in
// LDS, accumulate density+8 features in 9 VGPRs, write once (norm fused).
__global__ __launch_bounds__(64) void voxel_gather(
    const float* __restrict__ params,
    const int* __restrict__ counts, const int* __restrict__ entries,
    float* __restrict__ density, float* __restrict__ gfeat)
{
    __shared__ float gs[CAP][PSTRIDE];

    const int tile = blockIdx.x;
    const int seg  = tile % TZ;
    const int txy  = tile / TZ;
    const int ttx  = txy / TY, tty = txy % TY;
    const int tid  = threadIdx.x;
    const int cnt  = min(counts[tile], CAP);

    for (int j = tid; j < cnt; j += 64) {
        const int g = entries[tile * CAP + j];
        const float* P = params + (size_t)g * PSTRIDE;
        float* G = gs[j];
        #pragma unroll
        for (int q = 0; q < 5; ++q)
            *(float4*)(G + 4*q) = *(const float4*)(P + 4*q);
    }
    __syncthreads();

    // lane -> voxel: vz fastest for coalesced stores
    const int lz = tid & 3, ly = (tid >> 2) & 3, lx = tid >> 4;
    const int vx = ttx * TILE + lx, vy = tty * TILE + ly, vz = seg * ZSEG + lz;
    const float cx = (float)vx * VS + VMINX + HVS;
    const float cy = (float)vy * VS + VMINY + HVS;
    const float cz = (float)vz * VS + VMINZ + HVS;

    float den = 0.f;
    float ft0 = 0.f, ft1 = 0.f, ft2 = 0.f, ft3 = 0.f;
    float ft4 = 0.f, ft5 = 0.f, ft6 = 0.f, ft7 = 0.f;

    for (int j = 0; j < cnt; ++j) {
        const float* G = gs[j];
        const int w0 = __float_as_int(G[10]);
        const int w1 = __float_as_int(G[11]);
        const int gx0 = w0 & 255, gy0 = (w0 >> 8) & 255, gz0 = (w0 >> 16) & 255;
        const int gx1 = w1 & 255, gy1 = (w1 >> 8) & 255, gz1 = (w1 >> 16) & 255;
        if (vx < gx0 || vx > gx1 || vy < gy0 || vy > gy1 || vz < gz0 || vz > gz1)
            continue;

        const float ddx = cx - G[6], ddy = cy - G[7], ddz = cz - G[8];
        const float maha = G[0]*ddx*ddx + G[3]*ddy*ddy + G[5]*ddz*ddz
                         + 2.f*(G[1]*ddx*ddy + G[2]*ddx*ddz + G[4]*ddy*ddz);
        const float w = G[9] * __expf(-0.5f * maha);
        den += w;
        ft0 += w * G[12]; ft1 += w * G[13]; ft2 += w * G[14]; ft3 += w * G[15];
        ft4 += w * G[16]; ft5 += w * G[17]; ft6 += w * G[18]; ft7 += w * G[19];
    }

    const int flat = (vx * GY + vy) * GZ + vz;
    density[flat] = den;
    const float inv = 1.f / fmaxf(den, 1e-6f);
    float4 a = make_float4(ft0*inv, ft1*inv, ft2*inv, ft3*inv);
    float4 b = make_float4(ft4*inv, ft5*inv, ft6*inv, ft7*inv);
    *(float4*)(gfeat + (size_t)flat * 8)     = a;
    *(float4*)(gfeat + (size_t)flat * 8 + 4) = b;
}

extern "C" void kernel_launch(void* const* d_in, const int* in_sizes, int n_in,
                              void* d_out, int out_size, void* d_ws, size_t ws_size,
                              hipStream_t stream)
{
    const float* means  = (const float*)d_in[0];
    const float* opacs  = (const float*)d_in[1];
    const float* scales = (const float*)d_in[2];
    const float* rots   = (const float*)d_in[3];
    const float* feats  = (const float*)d_in[4];

    float* density = (float*)d_out;           // [V]
    float* gfeat   = density + NVOX;          // [V, 8]
    const int N = in_sizes[0] / 3;            // means3d is [B, N, 3], B=1

    int*   counts  = (int*)d_ws;              // [12500]
    int*   entries = counts + NTILES;         // [12500 * 128]
    float* params  = (float*)(entries + (size_t)NTILES * CAP);  // [N * 20]

    // ws is poisoned 0xAA before every timed call; zero the tile counters
    hipMemsetAsync(counts, 0, NTILES * sizeof(int), stream);

    voxel_bin<<<(N + 63) / 64, 64, 0, stream>>>(means, opacs, scales, rots, feats,
                                                counts, entries, params, N);
    voxel_gather<<<NTILES, 64, 0, stream>>>(params, counts, entries, density, gfeat);
}